// Round 7
// baseline (2710.965 us; speedup 1.0000x reference)
//
#include <hip/hip_runtime.h>
#include <cmath>

#define BATCH 2048
#define TSTEPS 16384

#define L2E 1.4426950408889634074
#define DTC 0.02

// Uniform per-slot rate form (DT and log2e folded):
//   e = 2^(A2*V + B2);   r' = DT*rate = (Cd + Dd*V) * e / (P + Q*e)
// slots: 0=alpha_m 1=beta_m 2=alpha_h 3=beta_h 4=alpha_n 5=beta_n 6,7=spare
__device__ __constant__ double CA2[8] = {0.1*L2E, -(1.0/18.0)*L2E, -0.05*L2E, 0.1*L2E, 0.1*L2E, -0.0125*L2E, 0.0, 0.0};
__device__ __constant__ double CB2[8] = {4.0*L2E, -(65.0/18.0)*L2E, -3.25*L2E, 3.5*L2E, 5.5*L2E, -0.8125*L2E, 0.0, 0.0};
__device__ __constant__ double CCd[8] = {DTC*4.0, DTC*4.0, DTC*0.07, DTC*1.0, DTC*0.55, DTC*0.125, DTC, DTC};
__device__ __constant__ double CDd[8] = {DTC*0.1, 0.0, 0.0, 0.0, DTC*0.01, 0.0, 0.0, 0.0};
__device__ __constant__ double CP[8]  = {-1.0, 1.0, 1.0, 1.0, -1.0, 1.0, 1.0, 1.0};
__device__ __constant__ double CQ[8]  = {1.0+1e-8, 0.0, 0.0, 1.0, 1.0+1e-8, 0.0, 0.0, 0.0};
__device__ __constant__ double CFV[8] = {-40.0, 1e300, 1e300, 1e300, -55.0, 1e300, 1e300, 1e300};
__device__ __constant__ double CFR[8] = {DTC*1.0, 0.0, 0.0, 0.0, DTC*0.1, 0.0, 0.0, 0.0};

// exp2 in f64: magic-number reduction + deg-9 even/odd Taylor + exponent injection.
__device__ __forceinline__ double exp2d(double y) {
    const double C52 = 6755399441055744.0;      // 1.5 * 2^52
    double z  = y + C52;
    double nf = z - C52;                         // round-to-nearest(y)
    double t  = y - nf;                          // exact, in [-0.5, 0.5]
    int    i  = __double2loint(z);               // integer part, two's complement
    double u  = t * t;
    double q = fma(u, 1.3215486790144309e-6, 1.5403530393381610e-4);
    q = fma(u, q, 9.6181291076284772e-3);
    q = fma(u, q, 2.4022650695910071e-1);
    q = fma(u, q, 1.0);
    double s = fma(u, 1.0178086009239696e-7, 1.5252733804059840e-5);
    s = fma(u, s, 1.3333558146428443e-3);
    s = fma(u, s, 5.5504108664821580e-2);
    s = fma(u, s, 6.9314718055994531e-1);
    double p = fma(t, s, q);                     // in [0.70, 1.42]
    int hi = __double2hiint(p) + (i << 20);      // multiply by 2^i via exponent add
    return __hiloint2double(hi, __double2loint(p));
}

__device__ __forceinline__ double rcp64(double d) {
#if __has_builtin(__builtin_amdgcn_rcp)
    double x = __builtin_amdgcn_rcp(d);
#else
    double x; asm("v_rcp_f64 %0, %1" : "=v"(x) : "v"(d));
#endif
    return fma(x, fma(-d, x, 1.0), x);           // 2^-29 seed -> ~2^-52
}

// DPP lane exchange within quads (VALU latency, no lgkmcnt)
#define QP_XOR1 0xB1   // quad_perm [1,0,3,2]  : lane ^ 1
#define QP_XOR2 0x4E   // quad_perm [2,3,0,1]  : lane ^ 2
#define QP_BC0  0x00   // quad_perm [0,0,0,0]  : broadcast quad-lane 0
template<int CTRL>
__device__ __forceinline__ double dpp_f64(double v) {
    int lo = __double2loint(v), hi = __double2hiint(v);
    lo = __builtin_amdgcn_update_dpp(lo, lo, CTRL, 0xF, 0xF, false);
    hi = __builtin_amdgcn_update_dpp(hi, hi, CTRL, 0xF, 0xF, false);
    return __hiloint2double(hi, lo);
}
// the single remaining cross-quad exchange: lane ^ 4 via ds_swizzle
__device__ __forceinline__ double swz_xor4_f64(double v) {
    int lo = __builtin_amdgcn_ds_swizzle(__double2loint(v), 0x101F);
    int hi = __builtin_amdgcn_ds_swizzle(__double2hiint(v), 0x101F);
    return __hiloint2double(hi, lo);
}

__global__ __launch_bounds__(64, 1)
void hh8s_kernel(const float* __restrict__ I,
                 const float* __restrict__ rgNa,
                 const float* __restrict__ rgK,
                 const float* __restrict__ rgL,
                 float* __restrict__ out)
{
    const int lane = threadIdx.x;               // block == 1 wave
    const int slot = lane & 7;
    const int nb   = blockIdx.x * 8 + (lane >> 3);
    const bool hiq = (lane & 4) != 0;           // upper quad of the 8-lane group

    const double A2 = CA2[slot], B2 = CB2[slot];
    const double Cd = CCd[slot], Dd = CDd[slot];
    const double P  = CP[slot],  Q  = CQ[slot];
    const double fixV = CFV[slot], fixR = CFR[slot];

    // softplus(x) = max(x,0) + log1p(exp(-|x|))
    double gNa, gK, gL;
    {
        double x = (double)rgNa[0]; gNa = fmax(x, 0.0) + log1p(exp(-fabs(x)));
        x = (double)rgK[0];         gK  = fmax(x, 0.0) + log1p(exp(-fabs(x)));
        x = (double)rgL[0];         gL  = fmax(x, 0.0) + log1p(exp(-fabs(x)));
    }
    const double kNa = DTC * gNa;
    const double kK  = DTC * gK;
    const double K1  = 1.0 - DTC * gL;
    const double K2  = -54.387 * (DTC * gL);
    // per-lane mirrored constants: both quads compute bit-identical V-updates
    const double kA = hiq ? kK  : kNa;   // multiplies Aq (A on loq, B on hiq)
    const double kB = hiq ? kNa : kK;    // multiplies Bw
    const double cA = hiq ? -77.0 : 50.0;
    const double cB = hiq ? 50.0 : -77.0;

    auto rate = [&](double Vx) -> double {
        double e   = exp2d(fma(A2, Vx, B2));
        double num = fma(Dd, Vx, Cd) * e;
        double den = fma(Q, e, P);
        double r0  = num * rcp64(den);
        return (fabs(Vx - fixV) < 1e-6) ? fixR : r0;
    };

    // ---- pipeline registers ----
    // V  = V_k          r = DT*rate(V_k)      g = own gate (state k)
    // Aq/Bw = broadcast m^3*h and n^4 of state k (Aq: own-quad value, Bw: crossed)
    double V = -65.0;
    double r = rate(V);
    double g, Aq, Bw;
    {
        double rb = dpp_f64<QP_XOR1>(r);
        g = r / (r + rb);                   // alpha/(alpha+beta) on even lanes
        double gg  = g * g;
        double gx  = dpp_f64<QP_XOR2>(g);
        double gxx = hiq ? g : gx;
        double w   = g * gxx;               // lane0: m*h    lane4: n*n
        double tt  = gg * w;                // lane0: m^3*h  lane4: n^4
        Aq = dpp_f64<QP_BC0>(tt);           // loq: A, hiq: B
        Bw = swz_xor4_f64(Aq);              // loq: B, hiq: A
    }

    const float* __restrict__ Ip = I + (size_t)nb * TSTEPS;
    float*       __restrict__ Op = out + (size_t)nb * TSTEPS + slot;

    // One Euler step, ordered so every consumer is far from its producer:
    //  [1] V-update   (Aq/Bw from last iter, DS latency long covered)
    //  [2] rate(Vn)   (tail latency lands next iter at [3])
    //  [3] gate commit (consumes r issued LAST iter's [2])
    //  [4] products + A/B broadcast (consumed next iter's [1])
    auto step = [&](float It) {
        // [1] V-update (lane-symmetric, bit-identical across the group)
        double pq  = kA * Aq;
        double pw  = kB * Bw;
        double u1  = cA * pq;
        double u2  = cB * pw;
        double sab = pq + pw;                // a+b  (commutative -> uniform)
        double t12 = u1 + u2;                // 50a-77b (commutative)
        double S1  = K1 - sab;
        double S2  = t12 + K2;
        double Vn  = fma(V, S1, fma(DTC, (double)It, S2));
        // [2] next-step rate (long chain, issued early)
        double rn  = rate(Vn);
        // [3] gate commit with current r (rates at V_k)
        double rb  = dpp_f64<QP_XOR1>(r);
        double sr  = r + rb;
        double gn  = fma(-sr, g, g + r);
        // [4] products from new gates -> A/B for next iter
        double gg  = gn * gn;
        double gx  = dpp_f64<QP_XOR2>(gn);
        double gxx = hiq ? gn : gx;
        double w   = gn * gxx;
        double tt  = gg * w;
        double qv  = dpp_f64<QP_BC0>(tt);
        double wv  = swz_xor4_f64(qv);
        // commit
        V = Vn; r = rn; g = gn; Aq = qv; Bw = wv;
    };

    const int NCH = TSTEPS / 8;
    float4 ia = reinterpret_cast<const float4*>(Ip)[0];
    float4 ib = reinterpret_cast<const float4*>(Ip)[1];

    for (int c = 0; c < NCH - 1; ++c) {
        const float cur[8] = {ia.x, ia.y, ia.z, ia.w, ib.x, ib.y, ib.z, ib.w};
        ia = reinterpret_cast<const float4*>(Ip)[2 * (c + 1)];
        ib = reinterpret_cast<const float4*>(Ip)[2 * (c + 1) + 1];
        float vs = 0.0f;
        #pragma unroll
        for (int j = 0; j < 8; ++j) {
            vs = (slot == j) ? (float)V : vs;   // out[p] = V after p steps
            step(cur[j]);
        }
        Op[c * 8] = vs;
    }
    // epilogue chunk: save 8 positions, step only the first 7 (I[T-1] unused)
    {
        const float cur[8] = {ia.x, ia.y, ia.z, ia.w, ib.x, ib.y, ib.z, ib.w};
        float vs = 0.0f;
        #pragma unroll
        for (int j = 0; j < 8; ++j) {
            vs = (slot == j) ? (float)V : vs;
            if (j < 7) step(cur[j]);
        }
        Op[(NCH - 1) * 8] = vs;
    }
}

extern "C" void kernel_launch(void* const* d_in, const int* in_sizes, int n_in,
                              void* d_out, int out_size, void* d_ws, size_t ws_size,
                              hipStream_t stream) {
    const float* I    = (const float*)d_in[0];
    const float* rgNa = (const float*)d_in[1];
    const float* rgK  = (const float*)d_in[2];
    const float* rgL  = (const float*)d_in[3];
    float* out = (float*)d_out;

    hh8s_kernel<<<dim3(BATCH / 8), dim3(64), 0, stream>>>(I, rgNa, rgK, rgL, out);
}

// Round 8
// 2387.150 us; speedup vs baseline: 1.1356x; 1.1356x over previous
//
#include <hip/hip_runtime.h>
#include <cmath>

#define BATCH 2048
#define TSTEPS 16384

#define L2E 1.4426950408889634074
#define DTC 0.02

// Uniform per-slot rate form (DT and log2e folded):
//   e = 2^(A2*V + B2);   r' = DT*rate = (Cd + Dd*V) * e / (P + Q*e)
// slots: 0=alpha_m 1=beta_m 2=alpha_h 3=beta_h 4=alpha_n 5=beta_n 6,7=spare
__device__ __constant__ double CA2[8] = {0.1*L2E, -(1.0/18.0)*L2E, -0.05*L2E, 0.1*L2E, 0.1*L2E, -0.0125*L2E, 0.0, 0.0};
__device__ __constant__ double CB2[8] = {4.0*L2E, -(65.0/18.0)*L2E, -3.25*L2E, 3.5*L2E, 5.5*L2E, -0.8125*L2E, 0.0, 0.0};
__device__ __constant__ double CCd[8] = {DTC*4.0, DTC*4.0, DTC*0.07, DTC*1.0, DTC*0.55, DTC*0.125, DTC, DTC};
__device__ __constant__ double CDd[8] = {DTC*0.1, 0.0, 0.0, 0.0, DTC*0.01, 0.0, 0.0, 0.0};
__device__ __constant__ double CP[8]  = {-1.0, 1.0, 1.0, 1.0, -1.0, 1.0, 1.0, 1.0};
__device__ __constant__ double CQ[8]  = {1.0+1e-8, 0.0, 0.0, 1.0, 1.0+1e-8, 0.0, 0.0, 0.0};
__device__ __constant__ double CFV[8] = {-40.0, 1e300, 1e300, 1e300, -55.0, 1e300, 1e300, 1e300};
__device__ __constant__ double CFR[8] = {DTC*1.0, 0.0, 0.0, 0.0, DTC*0.1, 0.0, 0.0, 0.0};

__device__ __forceinline__ float hw_exp2(float x) {
#if __has_builtin(__builtin_amdgcn_exp2f)
    return __builtin_amdgcn_exp2f(x);
#else
    float r; asm("v_exp_f32 %0, %1" : "=v"(r) : "v"(x)); return r;
#endif
}
__device__ __forceinline__ float rcp32(float d) {
#if __has_builtin(__builtin_amdgcn_rcpf)
    float x = __builtin_amdgcn_rcpf(d);
#else
    float x; asm("v_rcp_f32 %0, %1" : "=v"(x) : "v"(d));
#endif
    return fmaf(x, fmaf(-d, x, 1.0f), x);   // 1 NR: ~0.5 ulp
}

// f64 lane exchange within 8-groups via ds_swizzle (BitMode)
template<int PAT>
__device__ __forceinline__ double swz_f64(double v) {
    int lo = __builtin_amdgcn_ds_swizzle(__double2loint(v), PAT);
    int hi = __builtin_amdgcn_ds_swizzle(__double2hiint(v), PAT);
    return __hiloint2double(hi, lo);
}
__device__ __forceinline__ float swz_f32(float v, int pat_dummy) { return v; }
#define SWZ_XOR1  0x041F              // lane ^ 1
#define SWZ_BC(k) (((k) << 5) | 0x18) // broadcast lane (base|k) within 8-group

__global__ __launch_bounds__(64, 1)
void hh8t_kernel(const float* __restrict__ I,
                 const float* __restrict__ rgNa,
                 const float* __restrict__ rgK,
                 const float* __restrict__ rgL,
                 float* __restrict__ out)
{
    const int lane = threadIdx.x;               // block == 1 wave
    const int slot = lane & 7;
    const int nb   = blockIdx.x * 8 + (lane >> 3);
    const bool canc = (slot == 0) || (slot == 4);   // den = e-1+eps slots

    const double A2 = CA2[slot], B2 = CB2[slot];
    const double Cd = CCd[slot], Dd = CDd[slot];
    const double fixV = CFV[slot];
    const float  P32 = (float)CP[slot], Q32 = (float)CQ[slot];
    const float  fixR32 = (float)CFR[slot];

    // softplus(x) = max(x,0) + log1p(exp(-|x|))
    double gNa, gK, gL;
    {
        double x = (double)rgNa[0]; gNa = fmax(x, 0.0) + log1p(exp(-fabs(x)));
        x = (double)rgK[0];         gK  = fmax(x, 0.0) + log1p(exp(-fabs(x)));
        x = (double)rgL[0];         gL  = fmax(x, 0.0) + log1p(exp(-fabs(x)));
    }
    const double kNa = DTC * gNa;
    const double kK  = DTC * gK;
    const double K1  = 1.0 - DTC * gL;
    const double K2  = -54.387 * (DTC * gL);

    // Mixed-precision rate: f64 argument + range reduction (exact), hw f32 exp2,
    // f32 num/den/rcp.  Cancellation slots (den = e-1+1e-8e) use an accurate
    // 2^t-1 = t*P(t) poly when |y|<0.5 (i==0), so den keeps ~5e-7 REL error
    // even as den -> 0 near V = -40 / -55.
    auto rate = [&](double Vx) -> float {
        const double C52 = 6755399441055744.0;   // 1.5*2^52
        double y  = fma(A2, Vx, B2);
        double z  = y + C52;
        double nf = z - C52;                     // round-to-nearest(y)
        double t  = y - nf;                      // exact, [-0.5, 0.5]
        int    i  = __double2loint(z);
        float  t32 = (float)t;
        float  p32 = hw_exp2(t32);               // 2^t, ~1 ulp
        float  e32 = __int_as_float(__float_as_int(p32) + (i << 23));  // *2^i
        // (2^t - 1)/t  Taylor, f32:
        float P5 = fmaf(t32, 1.5403530e-4f, 1.3333558e-3f);
        P5 = fmaf(t32, P5, 9.6181291e-3f);
        P5 = fmaf(t32, P5, 5.5504109e-2f);
        P5 = fmaf(t32, P5, 2.4022651e-1f);
        P5 = fmaf(t32, P5, 6.9314718e-1f);
        float em1 = t32 * P5;                    // 2^t - 1, full rel precision
        float den_a = fmaf(Q32, e32, P32);
        float den_b = fmaf(1e-8f, e32, em1);     // e-1+1e-8e without cancellation
        float den = (canc && (i == 0)) ? den_b : den_a;
        float num = (float)fma(Dd, Vx, Cd) * e32;
        float r0  = num * rcp32(den);
        return (fabs(Vx - fixV) < 1e-6) ? fixR32 : r0;
    };

    double V = -65.0;
    float  r = rate(V);                  // pipelined: r == DT*rate(V_cur), f32
    double g, m, h, n;                   // g = own gate (valid on even lanes)
    {
        float rbf = __int_as_float(__builtin_amdgcn_ds_swizzle(__float_as_int(r), SWZ_XOR1));
        double rd = (double)r, rbd = (double)rbf;
        g = rd / (rd + rbd);             // alpha/(alpha+beta) on even lanes
        m = swz_f64<SWZ_BC(0)>(g);
        h = swz_f64<SWZ_BC(2)>(g);
        n = swz_f64<SWZ_BC(4)>(g);
    }

    const float* __restrict__ Ip = I + (size_t)nb * TSTEPS;
    float*       __restrict__ Op = out + (size_t)nb * TSTEPS + slot;

    // r5-proven step order: xor early, V-update (old gates), gate commit,
    // broadcasts (covered by rate chain), rate last.
    auto step = [&](float It) {
        float rbf = __int_as_float(__builtin_amdgcn_ds_swizzle(__float_as_int(r), SWZ_XOR1));
        // ---- V-update from OLD gates (f64) ----
        double mm  = m * m,  mh = m * h;
        double m3h = mm * mh;
        double nn  = n * n;
        double n4  = nn * nn;
        double a   = kNa * m3h;
        double b   = kK * n4;
        double S1  = (K1 - a) - b;
        double S2  = fma(-77.0, b, fma(50.0, a, K2));
        double Vn  = fma(V, S1, fma(DTC, (double)It, S2));
        // ---- gate update on own lane (f64, rates promoted) ----
        double rd  = (double)r, rbd = (double)rbf;
        double sr  = rd + rbd;
        g = fma(-sr, g, g + rd);
        // ---- broadcast new gates (latency covered by rate chain below) ----
        m = swz_f64<SWZ_BC(0)>(g);
        h = swz_f64<SWZ_BC(2)>(g);
        n = swz_f64<SWZ_BC(4)>(g);
        // ---- next-step rate (short mixed-precision chain) ----
        r = rate(Vn);
        V = Vn;
    };

    const int NCH = TSTEPS / 8;
    float4 ia = reinterpret_cast<const float4*>(Ip)[0];
    float4 ib = reinterpret_cast<const float4*>(Ip)[1];

    for (int c = 0; c < NCH - 1; ++c) {
        const float cur[8] = {ia.x, ia.y, ia.z, ia.w, ib.x, ib.y, ib.z, ib.w};
        ia = reinterpret_cast<const float4*>(Ip)[2 * (c + 1)];
        ib = reinterpret_cast<const float4*>(Ip)[2 * (c + 1) + 1];
        float vs = 0.0f;
        #pragma unroll
        for (int j = 0; j < 8; ++j) {
            vs = (slot == j) ? (float)V : vs;   // out[p] = V after p steps
            step(cur[j]);
        }
        Op[c * 8] = vs;
    }
    // epilogue chunk: save 8 positions, step only the first 7 (I[T-1] unused)
    {
        const float cur[8] = {ia.x, ia.y, ia.z, ia.w, ib.x, ib.y, ib.z, ib.w};
        float vs = 0.0f;
        #pragma unroll
        for (int j = 0; j < 8; ++j) {
            vs = (slot == j) ? (float)V : vs;
            if (j < 7) step(cur[j]);
        }
        Op[(NCH - 1) * 8] = vs;
    }
}

extern "C" void kernel_launch(void* const* d_in, const int* in_sizes, int n_in,
                              void* d_out, int out_size, void* d_ws, size_t ws_size,
                              hipStream_t stream) {
    const float* I    = (const float*)d_in[0];
    const float* rgNa = (const float*)d_in[1];
    const float* rgK  = (const float*)d_in[2];
    const float* rgL  = (const float*)d_in[3];
    float* out = (float*)d_out;

    hh8t_kernel<<<dim3(BATCH / 8), dim3(64), 0, stream>>>(I, rgNa, rgK, rgL, out);
}